// Round 2
// baseline (1333.395 us; speedup 1.0000x reference)
//
#include <hip/hip_runtime.h>

#define BATCH 256
#define TSTEPS 2048
#define INSZ 64
#define HID 128
#define OUTSZ 64
#define HPAD 68   // float offset of the s=1 half: 68%32=4 -> disjoint banks vs s=0

// One workgroup per batch element; 256 threads = (j=tid>>1 output, s=tid&1 k-half).
// Wh/Wx row-halves in registers; h double-buffered in LDS (bank-conflict-free
// padded layout); x prefetched global->registers one step ahead (no LDS, no
// staging; L1/L2-resident, latency hidden by the full step).
__launch_bounds__(256, 1)
__global__ void rnn_fused_kernel(const float* __restrict__ x,
                                 const float* __restrict__ Wx_w,
                                 const float* __restrict__ Wx_b,
                                 const float* __restrict__ Wh_w,
                                 const float* __restrict__ Wh_b,
                                 const float* __restrict__ fc_w,
                                 const float* __restrict__ fc_b,
                                 float* __restrict__ out) {
  const int b = blockIdx.x;
  const int tid = threadIdx.x;
  const int s = tid & 1;   // k-half: 0 -> k in [0,64), 1 -> k in [64,128)
  const int j = tid >> 1;  // hidden output index 0..127
  const int jp = j + ((j >> 6) << 2);  // padded h index (j>=64 shifted by +4)

  __shared__ __align__(16) float hbuf[2][2 * HPAD];  // 136 floats each

  // ---- preload weights into registers ----
  float wh[64];
  const float* whp = Wh_w + j * HID + s * 64;
#pragma unroll
  for (int i = 0; i < 64; i += 4) *(float4*)&wh[i] = *(const float4*)&whp[i];

  float wx[32];
  const float* wxp = Wx_w + j * INSZ + s * 32;
#pragma unroll
  for (int i = 0; i < 32; i += 4) *(float4*)&wx[i] = *(const float4*)&wxp[i];

  const float bc = Wx_b[j] + Wh_b[j];  // combined bias

  const float* xg = x + (size_t)b * TSTEPS * INSZ;

  // ---- init h0 = 0 (including pad region) ----
  if (tid < 2 * HPAD) hbuf[0][tid] = 0.f;

  // ---- prefetch x[0] into registers ----
  float4 xrA[8], xrB[8];
  {
    const float4* xsrc = (const float4*)xg + s * 8;
#pragma unroll
    for (int i = 0; i < 8; ++i) xrA[i] = xsrc[i];
  }
  __syncthreads();

  auto step = [&](int tt, const float* hin, float* hout,
                  const float4* xcur, float4* xnext) {
    // issue h reads early (latency overlaps the x-part FMAs below)
    const float* hs = hin + s * HPAD;
    float4 hv[16];
#pragma unroll
    for (int i = 0; i < 16; ++i) hv[i] = *(const float4*)&hs[i * 4];

    // prefetch x for the NEXT step (consumed next iteration; latency hidden)
    int tn = tt + 1; if (tn >= TSTEPS) tn = TSTEPS - 1;
    const float4* xsrc = (const float4*)(xg + (size_t)tn * INSZ) + s * 8;
#pragma unroll
    for (int i = 0; i < 8; ++i) xnext[i] = xsrc[i];

    // x-part first (no h dependency)
    float a0 = 0.f, a1 = 0.f, a2 = 0.f, a3 = 0.f;
#pragma unroll
    for (int i = 0; i < 8; ++i) {
      a0 = fmaf(wx[4 * i + 0], xcur[i].x, a0);
      a1 = fmaf(wx[4 * i + 1], xcur[i].y, a1);
      a2 = fmaf(wx[4 * i + 2], xcur[i].z, a2);
      a3 = fmaf(wx[4 * i + 3], xcur[i].w, a3);
    }
    // h-part
#pragma unroll
    for (int i = 0; i < 16; ++i) {
      a0 = fmaf(wh[4 * i + 0], hv[i].x, a0);
      a1 = fmaf(wh[4 * i + 1], hv[i].y, a1);
      a2 = fmaf(wh[4 * i + 2], hv[i].z, a2);
      a3 = fmaf(wh[4 * i + 3], hv[i].w, a3);
    }
    float acc = (a0 + a1) + (a2 + a3);
    acc += __shfl_xor(acc, 1, 64);  // combine the two k-halves (lanes 2j, 2j+1)

    // h_new = tanh(z) = 1 - 2/(exp2(2*z*log2e)+1)
    float z = acc + bc;
    float e = __builtin_amdgcn_exp2f(z * 2.885390081777927f);
    float hn = 1.f - 2.f * __builtin_amdgcn_rcpf(e + 1.f);

    if (s == 0) hout[jp] = hn;
    __syncthreads();
  };

  // ---- recurrence: unrolled x2 so buffer parities are compile-time static ----
  for (int t = 0; t < TSTEPS; t += 2) {
    step(t,     hbuf[0], hbuf[1], xrA, xrB);
    step(t + 1, hbuf[1], hbuf[0], xrB, xrA);
  }

  // ---- epilogue: logits = h_T @ fc_w^T + fc_b, softmax over 64, one wave ----
  // T even -> final h is in hbuf[0] (padded layout)
  if (tid < 64) {
    float a = fc_b[tid];
    const float* fr = fc_w + tid * HID;
#pragma unroll
    for (int k = 0; k < HID; k += 4) {
      float4 w4 = *(const float4*)&fr[k];
      const float* hf = &hbuf[0][k + ((k >> 6) << 2)];
      a = fmaf(w4.x, hf[0], a);
      a = fmaf(w4.y, hf[1], a);
      a = fmaf(w4.z, hf[2], a);
      a = fmaf(w4.w, hf[3], a);
    }
    float m = a;
#pragma unroll
    for (int off = 32; off >= 1; off >>= 1) m = fmaxf(m, __shfl_xor(m, off, 64));
    float e = __builtin_amdgcn_exp2f((a - m) * 1.4426950408889634f);
    float ssum = e;
#pragma unroll
    for (int off = 32; off >= 1; off >>= 1) ssum += __shfl_xor(ssum, off, 64);
    out[b * OUTSZ + tid] = e / ssum;
  }
}

extern "C" void kernel_launch(void* const* d_in, const int* in_sizes, int n_in,
                              void* d_out, int out_size, void* d_ws, size_t ws_size,
                              hipStream_t stream) {
  const float* x    = (const float*)d_in[0];
  const float* Wx_w = (const float*)d_in[1];
  const float* Wx_b = (const float*)d_in[2];
  const float* Wh_w = (const float*)d_in[3];
  const float* Wh_b = (const float*)d_in[4];
  const float* fc_w = (const float*)d_in[5];
  const float* fc_b = (const float*)d_in[6];
  float* out = (float*)d_out;

  rnn_fused_kernel<<<BATCH, 256, 0, stream>>>(x, Wx_w, Wx_b, Wh_w, Wh_b, fc_w, fc_b, out);
}